// Round 3
// baseline (182.090 us; speedup 1.0000x reference)
//
#include <hip/hip_runtime.h>

// Problem: x [64,128,56,56] fp32; act_codes [C*H*W] int32 in [0,6).
// out[b, n] = act[act_codes[n]](x[b, n]) with n over C*H*W = 401408.
//
// R1: rcp/exp2 peephole ~0 net. R2: one-sigmoid structural cut ~0 net.
// Conclusion: not VALU-issue-bound at the whole-kernel level; residual is
// memory-system (codes re-read 64x = 103 MB, L3 flushed each iter by the
// harness's 411 MB poison fills, nt-store bypassing L2 write path).
// R3: ROWS=8 batching — load codes once per thread, process 8 batch rows;
// hoist all per-code constants out of the row loop; plain stores.

#define N4   100352   // (128*56*56)/4
#define GX   392      // N4 / 256
#define ROWS 8        // batch rows per thread
#define GY   8        // 64 / ROWS

typedef float f32x4 __attribute__((ext_vector_type(4)));

__global__ __launch_bounds__(256) void act_select_kernel(
    const f32x4* __restrict__ x,
    const int4*  __restrict__ codes,
    f32x4*       __restrict__ out)
{
    const float L2E = 1.4426950408889634f;     // log2(e)
    const float K0L = 1.5957691216f * L2E;     // 2*sqrt(2/pi) * log2e
    const float K1L = 0.0713548162f * L2E;     // 2*sqrt(2/pi)*0.044715 * log2e

    int n = blockIdx.x * 256 + threadIdx.x;    // [0, N4)
    int4 c = codes[n];                         // loaded ONCE for 8 rows
    int cc[4] = {c.x, c.y, c.z, c.w};

    // per-code constants, hoisted out of the row loop (compile-time indices
    // after unroll -> registers, not scratch)
    float tmL[4], aC[4], bC[4], ngC[4];
    bool  c5b[4], c3b[4], famb[4];
    #pragma unroll
    for (int i = 0; i < 4; ++i) {
        int ci = cc[i];
        bool c1 = ci == 1, c2 = ci == 2;
        c3b[i]  = ci == 3;
        c5b[i]  = ci == 5;
        famb[i] = c1 | c2 | c5b[i];
        tmL[i]  = c2 ? 2.f * L2E : L2E;        // log2e * (sigmoid-arg multiplier)
        aC[i]   = c2 ? 2.f : 1.f;              // fam = a*s + b
        bC[i]   = c2 ? -1.f : 0.f;
        ngC[i]  = (ci == 4) ? 0.01f : 0.f;     // leaky/relu negative slope
    }

    const f32x4* xb = x   + (size_t)blockIdx.y * ROWS * N4 + n;
    f32x4*       ob = out + (size_t)blockIdx.y * ROWS * N4 + n;

    #pragma unroll
    for (int r = 0; r < ROWS; ++r) {
        f32x4 v = xb[(size_t)r * N4];
        f32x4 o;
        #pragma unroll
        for (int i = 0; i < 4; ++i) {
            float xv  = v[i];
            float ax  = fabsf(xv);
            bool  pos = xv >= 0.f;

            // sigmoid-family core: e = exp(-|t|), t = x * tm
            //   c1 sigmoid: tm=1; c2 tanh: tm=2; c5 gelu: tm = 2u/x (poly)
            float tgL = fmaf(K1L, xv * xv, K0L);
            float tL  = c5b[i] ? tgL : tmL[i];
            float e   = __builtin_amdgcn_exp2f(-tL * ax);   // (0,1], stable
            float rc  = __builtin_amdgcn_rcpf(1.f + e);
            float s   = pos ? rc : e * rc;                  // sigmoid(t)

            // c1: s; c2: 2s-1; c5: x*s
            float a   = c5b[i] ? xv : aC[i];
            float fam = fmaf(a, s, bC[i]);

            // c0/c3/c4: pos side is x; neg side 0 / (exp(x)-1) / 0.01x
            float neg = c3b[i] ? (e - 1.f) : ngC[i] * xv;
            float tr  = pos ? xv : neg;

            o[i] = famb[i] ? fam : tr;
        }
        ob[(size_t)r * N4] = o;
    }
}

extern "C" void kernel_launch(void* const* d_in, const int* in_sizes, int n_in,
                              void* d_out, int out_size, void* d_ws, size_t ws_size,
                              hipStream_t stream) {
    const f32x4* x     = (const f32x4*)d_in[0];
    const int4*  codes = (const int4*)d_in[1];
    f32x4*       out   = (f32x4*)d_out;

    dim3 grid(GX, GY);
    act_select_kernel<<<grid, 256, 0, stream>>>(x, codes, out);
}

// Round 4
// 179.877 us; speedup vs baseline: 1.0123x; 1.0123x over previous
//
#include <hip/hip_runtime.h>

// Problem: x [64,128,56,56] fp32; act_codes [C*H*W] int32 in [0,6).
// out[b, n] = act[act_codes[n]](x[b, n]) with n over C*H*W = 401408.
//
// R1: rcp/exp2 peephole ~0. R2: one-sigmoid structural VALU cut ~0.
// R3: ROWS=8 batching -> VALUBusy 73->20% but dur 62us: VGPR=32 forced
//     load->vmcnt(0)->compute per row = one load in flight per wave,
//     latency-serialized.
// R4: prefetch-all/compute-all split. ROWS=4 loads issued back-to-back
//     into named registers (4 outstanding 1KB loads/wave), then compute.
//     Restores MLP; GY=16 doubles workgroup parallelism vs R3.

#define N4   100352   // (128*56*56)/4
#define GX   392      // N4 / 256
#define ROWS 4        // batch rows per thread
#define GY   16       // 64 / ROWS

typedef float f32x4 __attribute__((ext_vector_type(4)));

__global__ __launch_bounds__(256) void act_select_kernel(
    const f32x4* __restrict__ x,
    const int4*  __restrict__ codes,
    f32x4*       __restrict__ out)
{
    const float L2E = 1.4426950408889634f;     // log2(e)
    const float K0L = 1.5957691216f * L2E;     // 2*sqrt(2/pi) * log2e
    const float K1L = 0.0713548162f * L2E;     // .. * 0.044715

    int n = blockIdx.x * 256 + threadIdx.x;    // [0, N4)

    const f32x4* xb = x   + (size_t)blockIdx.y * ROWS * N4 + n;
    f32x4*       ob = out + (size_t)blockIdx.y * ROWS * N4 + n;

    // ---- issue ALL row loads first: 4 independent global_load_dwordx4 ----
    f32x4 v0 = xb[0];
    f32x4 v1 = xb[(size_t)1 * N4];
    f32x4 v2 = xb[(size_t)2 * N4];
    f32x4 v3 = xb[(size_t)3 * N4];
    int4  c  = codes[n];                       // loaded once for all rows

    int cc[4] = {c.x, c.y, c.z, c.w};

    // per-code constants, hoisted (static indices after unroll -> registers)
    float tmL[4], aC[4], bC[4], ngC[4];
    bool  c5b[4], c3b[4], famb[4];
    #pragma unroll
    for (int i = 0; i < 4; ++i) {
        int ci = cc[i];
        bool c1 = ci == 1, c2 = ci == 2;
        c3b[i]  = ci == 3;
        c5b[i]  = ci == 5;
        famb[i] = c1 | c2 | c5b[i];
        tmL[i]  = c2 ? 2.f * L2E : L2E;        // log2e * sigmoid-arg multiplier
        aC[i]   = c2 ? 2.f : 1.f;              // fam = a*s + b
        bC[i]   = c2 ? -1.f : 0.f;
        ngC[i]  = (ci == 4) ? 0.01f : 0.f;     // relu/leaky negative slope
    }

    f32x4 vr[ROWS] = {v0, v1, v2, v3};

    #pragma unroll
    for (int r = 0; r < ROWS; ++r) {
        f32x4 o;
        #pragma unroll
        for (int i = 0; i < 4; ++i) {
            float xv  = vr[r][i];
            float ax  = fabsf(xv);
            bool  pos = xv >= 0.f;

            // sigmoid-family core: e = exp(-|t|), t = x * tm
            //   c1 sigmoid: tm=1; c2 tanh: tm=2; c5 gelu: tm = 2u/x (poly)
            float tgL = fmaf(K1L, xv * xv, K0L);
            float tL  = c5b[i] ? tgL : tmL[i];
            float e   = __builtin_amdgcn_exp2f(-tL * ax);   // (0,1], stable
            float rc  = __builtin_amdgcn_rcpf(1.f + e);
            float s   = pos ? rc : e * rc;                  // sigmoid(t)

            // c1: s; c2: 2s-1; c5: x*s
            float a   = c5b[i] ? xv : aC[i];
            float fam = fmaf(a, s, bC[i]);

            // c0/c3/c4: pos side x; neg side 0 / (exp(x)-1) / 0.01x
            float neg = c3b[i] ? (e - 1.f) : ngC[i] * xv;
            float tr  = pos ? xv : neg;

            o[i] = famb[i] ? fam : tr;
        }
        // write-once stream: bypass caches, keep L3 for x
        __builtin_nontemporal_store(o, &ob[(size_t)r * N4]);
    }
}

extern "C" void kernel_launch(void* const* d_in, const int* in_sizes, int n_in,
                              void* d_out, int out_size, void* d_ws, size_t ws_size,
                              hipStream_t stream) {
    const f32x4* x     = (const f32x4*)d_in[0];
    const int4*  codes = (const int4*)d_in[1];
    f32x4*       out   = (f32x4*)d_out;

    dim3 grid(GX, GY);
    act_select_kernel<<<grid, 256, 0, stream>>>(x, codes, out);
}

// Round 5
// 179.606 us; speedup vs baseline: 1.0138x; 1.0015x over previous
//
#include <hip/hip_runtime.h>

// Problem: x [64,128,56,56] fp32; act_codes [C*H*W] int32 in [0,6).
// out[b, n] = act[act_codes[n]](x[b, n]) with n over C*H*W = 401408.
//
// R1 rcp/exp2: ~0. R2 one-sigmoid VALU cut: VALUBusy 73->20%, dur ~0.
// R3 ROWS=8: latency-serialized (VGPR=32). R4 prefetch-all: compiler SANK
// the loads (VGPR=24!) -> never executed; dur 61.6us unchanged.
// R5: pin the load cluster with sched_barrier(0). codes issued FIRST so
// constant setup waits only vmcnt(4) and overlaps the x-loads in flight.
// Plain stores (nt was neutral x3). Ideal = 103MB copy = ~33us @ 6.3TB/s.

#define N4   100352   // (128*56*56)/4
#define GX   392      // N4 / 256
#define ROWS 4        // batch rows per thread
#define GY   16       // 64 / ROWS

typedef float f32x4 __attribute__((ext_vector_type(4)));

__global__ __launch_bounds__(256) void act_select_kernel(
    const f32x4* __restrict__ x,
    const int4*  __restrict__ codes,
    f32x4*       __restrict__ out)
{
    const float L2E = 1.4426950408889634f;     // log2(e)
    const float K0L = 1.5957691216f * L2E;     // 2*sqrt(2/pi) * log2e
    const float K1L = 0.0713548162f * L2E;     // .. * 0.044715

    int n = blockIdx.x * 256 + threadIdx.x;    // [0, N4)
    size_t base = (size_t)blockIdx.y * ROWS * N4 + n;
    const f32x4* xb = x   + base;
    f32x4*       ob = out + base;

    // ---- load cluster: codes FIRST (wait vmcnt(4) covers only c), then
    // 4 independent x rows. sched_barrier(0) forbids the compiler from
    // sinking any of these below it (R4 failure mode: VGPR=24 proved sink).
    int4  c  = codes[n];
    f32x4 v0 = xb[0];
    f32x4 v1 = xb[(size_t)1 * N4];
    f32x4 v2 = xb[(size_t)2 * N4];
    f32x4 v3 = xb[(size_t)3 * N4];
    __builtin_amdgcn_sched_barrier(0);

    int cc[4] = {c.x, c.y, c.z, c.w};

    // per-code constants (needs only c -> overlaps x-loads in flight)
    float tmL[4], aC[4], bC[4], ngC[4];
    bool  c5b[4], c3b[4], famb[4];
    #pragma unroll
    for (int i = 0; i < 4; ++i) {
        int ci = cc[i];
        bool c1 = ci == 1, c2 = ci == 2;
        c3b[i]  = ci == 3;
        c5b[i]  = ci == 5;
        famb[i] = c1 | c2 | c5b[i];
        tmL[i]  = c2 ? 2.f * L2E : L2E;        // log2e * sigmoid-arg multiplier
        aC[i]   = c2 ? 2.f : 1.f;              // fam = a*s + b
        bC[i]   = c2 ? -1.f : 0.f;
        ngC[i]  = (ci == 4) ? 0.01f : 0.f;     // relu/leaky negative slope
    }

    f32x4 vr[ROWS] = {v0, v1, v2, v3};

    #pragma unroll
    for (int r = 0; r < ROWS; ++r) {
        f32x4 o;
        #pragma unroll
        for (int i = 0; i < 4; ++i) {
            float xv  = vr[r][i];
            float ax  = fabsf(xv);
            bool  pos = xv >= 0.f;

            // sigmoid-family core: e = exp(-|t|), t = x * tm
            //   c1 sigmoid: tm=1; c2 tanh: tm=2; c5 gelu: tm = 2u/x (poly)
            float tgL = fmaf(K1L, xv * xv, K0L);
            float tL  = c5b[i] ? tgL : tmL[i];
            float e   = __builtin_amdgcn_exp2f(-tL * ax);   // (0,1], stable
            float rc  = __builtin_amdgcn_rcpf(1.f + e);
            float s   = pos ? rc : e * rc;                  // sigmoid(t)

            // c1: s; c2: 2s-1; c5: x*s
            float a   = c5b[i] ? xv : aC[i];
            float fam = fmaf(a, s, bC[i]);

            // c0/c3/c4: pos side x; neg side 0 / (exp(x)-1) / 0.01x
            float neg = c3b[i] ? (e - 1.f) : ngC[i] * xv;
            float tr  = pos ? xv : neg;

            o[i] = famb[i] ? fam : tr;
        }
        ob[(size_t)r * N4] = o;   // plain store (nt neutral in R1/R2/R4)
    }
}

extern "C" void kernel_launch(void* const* d_in, const int* in_sizes, int n_in,
                              void* d_out, int out_size, void* d_ws, size_t ws_size,
                              hipStream_t stream) {
    const f32x4* x     = (const f32x4*)d_in[0];
    const int4*  codes = (const int4*)d_in[1];
    f32x4*       out   = (f32x4*)d_out;

    dim3 grid(GX, GY);
    act_select_kernel<<<grid, 256, 0, stream>>>(x, codes, out);
}